// Round 7
// baseline (299.921 us; speedup 1.0000x reference)
//
#include <hip/hip_runtime.h>

#define B_    8
#define N_    8192
#define S_    2048
#define D1_   128
#define D2_   256
#define CIN_  384
#define CMID_ 256
#define COUT_ 256

typedef unsigned int  u32;
typedef unsigned short u16;
typedef __attribute__((ext_vector_type(8))) short short8;
typedef __attribute__((ext_vector_type(4))) float f32x4;

static __device__ __forceinline__ u32 uminu(u32 a, u32 b) { return a < b ? a : b; }
static __device__ __forceinline__ u32 umaxu(u32 a, u32 b) { return a > b ? a : b; }
// compiles to v_med3_u32 via pattern match
static __device__ __forceinline__ u32 umed3(u32 a, u32 b, u32 c) {
  return umaxu(uminu(a, b), uminu(umaxu(a, b), c));
}
static __device__ __forceinline__ u16 f2bf(float f) {
  union { float f; u32 u; } v; v.f = f;
  u32 r = v.u + 0x7FFFu + ((v.u >> 16) & 1u);  // RNE
  return (u16)(r >> 16);
}
static __device__ __forceinline__ float bflo(u32 u) { return __uint_as_float(u << 16); }
static __device__ __forceinline__ float bfhi(u32 u) { return __uint_as_float(u & 0xFFFF0000u); }

#define GLD16(g, l)                                                             \
  __builtin_amdgcn_global_load_lds((const __attribute__((address_space(1))) void*)(g), \
                                   (__attribute__((address_space(3))) void*)(l), 16, 0, 0)

// ---------------------------------------------------------------------------
// Prep: pts4[b][s] = (-2x, -2y, -2z, |q|^2_f32)   (xyz recoverable exactly)
// ---------------------------------------------------------------------------
__global__ __launch_bounds__(256) void k_prep(const float* __restrict__ xyz2,
                                              float4* __restrict__ pts4) {
  const int b = blockIdx.y, s = blockIdx.x * 256 + threadIdx.x;
  const float* xb = xyz2 + (size_t)b * 3 * S_;
  float x = xb[s], y = xb[S_ + s], z = xb[2 * S_ + s];
  pts4[b * S_ + s] = make_float4(-2.f * x, -2.f * y, -2.f * z, x * x + y * y + z * z);
}

// ---------------------------------------------------------------------------
// NN screen: fp32 distance, packed key = (bits & 0xFFFFFF00) | s_local.
// TWO independent top-4 networks (even/odd s) break the serial insert chain
// (ILP 2), merged at the end. 8 chunks of 256 -> 8192 waves (8/SIMD).
// ---------------------------------------------------------------------------
__global__ __launch_bounds__(256) void k_nn_scan(const float* __restrict__ xyz1,
                                                 const float4* __restrict__ pts4,
                                                 uint4* __restrict__ keys) {
  const int b = blockIdx.z, chunk = blockIdx.y;
  const int n = blockIdx.x * 256 + threadIdx.x;
  const float* pb = xyz1 + (size_t)b * 3 * N_;
  const float px = pb[n], py = pb[N_ + n], pz = pb[2 * N_ + n];
  const float pn = px * px + py * py + pz * pz;
  const float4* __restrict__ P = pts4 + b * S_ + chunk * 256;
  u32 a0 = ~0u, a1 = ~0u, a2 = ~0u, a3 = ~0u;
  u32 c0 = ~0u, c1 = ~0u, c2 = ~0u, c3 = ~0u;
#pragma unroll 8
  for (int s = 0; s < 256; s += 2) {
    float4 q0 = P[s], q1 = P[s + 1];  // uniform -> s_load_dwordx4
    float d0 = fmaf(px, q0.x, fmaf(py, q0.y, fmaf(pz, q0.z, pn + q0.w)));
    float d1 = fmaf(px, q1.x, fmaf(py, q1.y, fmaf(pz, q1.z, pn + q1.w)));
    d0 = fmaxf(d0, 0.f);
    d1 = fmaxf(d1, 0.f);
    u32 k0 = (__float_as_uint(d0) & 0xFFFFFF00u) | (u32)s;
    u32 k1 = (__float_as_uint(d1) & 0xFFFFFF00u) | (u32)(s + 1);
    a3 = uminu(a3, umaxu(a2, k0)); a2 = umed3(a1, a2, k0);
    a1 = umed3(a0, a1, k0);        a0 = uminu(a0, k0);
    c3 = uminu(c3, umaxu(c2, k1)); c2 = umed3(c1, c2, k1);
    c1 = umed3(c0, c1, k1);        c0 = uminu(c0, k1);
  }
  u32 mk[4] = {c0, c1, c2, c3};
#pragma unroll
  for (int j = 0; j < 4; ++j) {
    u32 k = mk[j];
    a3 = uminu(a3, umaxu(a2, k)); a2 = umed3(a1, a2, k);
    a1 = umed3(a0, a1, k);        a0 = uminu(a0, k);
  }
  uint4 v; v.x = a0; v.y = a1; v.z = a2; v.w = a3;
  keys[((size_t)(b * 8 + chunk)) * N_ + n] = v;
}

// ---------------------------------------------------------------------------
// Refine: exact fp64 distances (reference formula) over the 32 candidates
// (8 chunks x top-4), lexicographic (d, idx) top-3 -> weights.
// ---------------------------------------------------------------------------
__global__ __launch_bounds__(256) void k_refine(const float* __restrict__ xyz1,
                                                const float4* __restrict__ pts4,
                                                const uint4* __restrict__ keys,
                                                int4* __restrict__ idx4,
                                                float4* __restrict__ w4) {
  const int b = blockIdx.y, n = blockIdx.x * 256 + threadIdx.x;
  const float* pb = xyz1 + (size_t)b * 3 * N_;
  const double px = (double)pb[n], py = (double)pb[N_ + n], pz = (double)pb[2 * N_ + n];
  const double pn = px * px + py * py + pz * pz;
  double bd0 = 1e300, bd1 = 1e300, bd2 = 1e300;
  int bi0 = 1 << 30, bi1 = 1 << 30, bi2 = 1 << 30;
#pragma unroll
  for (int c = 0; c < 8; ++c) {
    uint4 kk = keys[((size_t)(b * 8 + c)) * N_ + n];
    u32 arr[4] = {kk.x, kk.y, kk.z, kk.w};
#pragma unroll
    for (int j = 0; j < 4; ++j) {
      int s = c * 256 + (int)(arr[j] & 255u);
      float4 q = pts4[b * S_ + s];
      double x = (double)(q.x * -0.5f), y = (double)(q.y * -0.5f), z = (double)(q.z * -0.5f);
      double dot = px * x + py * y + pz * z;
      double d = -2.0 * dot + (pn + (x * x + y * y + z * z));
      if (d < bd2 || (d == bd2 && s < bi2)) {
        if (d < bd1 || (d == bd1 && s < bi1)) {
          bd2 = bd1; bi2 = bi1;
          if (d < bd0 || (d == bd0 && s < bi0)) { bd1 = bd0; bi1 = bi0; bd0 = d; bi0 = s; }
          else                                  { bd1 = d;  bi1 = s; }
        } else { bd2 = d; bi2 = s; }
      }
    }
  }
  float f0 = (float)bd0, f1 = (float)bd1, f2 = (float)bd2;
  float r0 = 1.f / (f0 + 1e-8f), r1 = 1.f / (f1 + 1e-8f), r2 = 1.f / (f2 + 1e-8f);
  float rs = r0 + r1 + r2;
  w4[(size_t)b * N_ + n]   = make_float4(r0 / rs, r1 / rs, r2 / rs, 0.f);
  idx4[(size_t)b * N_ + n] = make_int4(bi0, bi1, bi2, 0);
}

// ---------------------------------------------------------------------------
// Transpose points2 [b][256][2048] -> p2T [b][2048][256]  (fp32, LDS tiles)
// ---------------------------------------------------------------------------
__global__ __launch_bounds__(256) void k_p2t(const float* __restrict__ p2,
                                             float* __restrict__ p2T) {
  __shared__ float t[32][33];
  const int b = blockIdx.z, s0 = blockIdx.x * 32, d0 = blockIdx.y * 32;
  const int cc = threadIdx.x & 31, rr = threadIdx.x >> 5;  // 8 rows/pass
#pragma unroll
  for (int i = 0; i < 4; ++i) {
    int r = rr + i * 8;
    t[r][cc] = p2[((size_t)b * D2_ + d0 + r) * S_ + s0 + cc];
  }
  __syncthreads();
#pragma unroll
  for (int i = 0; i < 4; ++i) {
    int r = rr + i * 8;  // r = s-local
    p2T[((size_t)b * S_ + s0 + r) * D2_ + d0 + cc] = t[cc][r];
  }
}

// ---------------------------------------------------------------------------
// points1 [b][128][N] -> xT[b][n][0..127] bf16 (transpose + convert)
// ---------------------------------------------------------------------------
__global__ __launch_bounds__(256) void k_packp1(const float* __restrict__ p1,
                                                u16* __restrict__ xT) {
  __shared__ float t[32][33];
  const int b = blockIdx.z, n0 = blockIdx.x * 32, c0 = blockIdx.y * 32;
  const int cc = threadIdx.x & 31, rr = threadIdx.x >> 5;
#pragma unroll
  for (int i = 0; i < 4; ++i) {
    int r = rr + i * 8;
    t[r][cc] = p1[((size_t)b * D1_ + c0 + r) * N_ + n0 + cc];
  }
  __syncthreads();
#pragma unroll
  for (int i = 0; i < 4; ++i) {
    int r = rr + i * 8;  // r = n-local
    xT[((size_t)b * N_ + n0 + r) * CIN_ + c0 + cc] = f2bf(t[cc][r]);
  }
}

// ---------------------------------------------------------------------------
// Gather+interp into xT[b][n][128..383] bf16. One WAVE per point n.
// ---------------------------------------------------------------------------
__global__ __launch_bounds__(256) void k_gather_pack(const float* __restrict__ p2T,
                                                     const int4* __restrict__ idx4,
                                                     const float4* __restrict__ w4,
                                                     u16* __restrict__ xT) {
  const int b = blockIdx.y;
  const int wv = threadIdx.x >> 6, lane = threadIdx.x & 63;
  const int nbase = blockIdx.x * 16 + wv * 4;
  int4   id[4];
  float4 w[4];
#pragma unroll
  for (int i = 0; i < 4; ++i) {
    id[i] = idx4[(size_t)b * N_ + nbase + i];  // wave-uniform broadcast
    w[i]  = w4[(size_t)b * N_ + nbase + i];
  }
#pragma unroll
  for (int i = 0; i < 4; ++i) {
    const int n = nbase + i;
    const float4* r0 = (const float4*)(p2T + ((size_t)b * S_ + id[i].x) * D2_) + lane;
    const float4* r1 = (const float4*)(p2T + ((size_t)b * S_ + id[i].y) * D2_) + lane;
    const float4* r2 = (const float4*)(p2T + ((size_t)b * S_ + id[i].z) * D2_) + lane;
    float4 a = *r0, bb = *r1, cq = *r2;
    ushort4 pk;
    pk.x = f2bf(a.x * w[i].x + bb.x * w[i].y + cq.x * w[i].z);
    pk.y = f2bf(a.y * w[i].x + bb.y * w[i].y + cq.y * w[i].z);
    pk.z = f2bf(a.z * w[i].x + bb.z * w[i].y + cq.z * w[i].z);
    pk.w = f2bf(a.w * w[i].x + bb.w * w[i].y + cq.w * w[i].z);
    *(ushort4*)(xT + ((size_t)b * N_ + n) * CIN_ + D1_ + lane * 4) = pk;
  }
}

// ---------------------------------------------------------------------------
// Convert w1, w2 to bf16 (row-major, k-contiguous)
// ---------------------------------------------------------------------------
__global__ __launch_bounds__(256) void k_wcvt(const float* __restrict__ w1,
                                              const float* __restrict__ w2,
                                              u16* __restrict__ w1b,
                                              u16* __restrict__ w2b) {
  int i = blockIdx.x * 256 + threadIdx.x;
  if (i < CMID_ * CIN_) w1b[i] = f2bf(w1[i]);
  int j = i - CMID_ * CIN_;
  if (j >= 0 && j < COUT_ * CMID_) w2b[j] = f2bf(w2[j]);
}

// ---------------------------------------------------------------------------
// GEMM1 (bf16 MFMA): y1T[b][n][o] = bf16( w1[o][:] . xT[b][n][:] + b1[o] )
// 128x128 tile, 4 waves, BK=32, global_load_lds width-16.
// LDS k-chunk XOR swizzle (phys = log ^ ((row>>1)&3)): fragment ds_read_b128
// goes 8-way-conflict -> 2-way (free). Staging permutes the SOURCE k-chunk
// per lane so the GLD16 lane-contiguous LDS write lands swizzled.
// Fused BN1 stats via shfl_xor butterfly + distinct-address LDS atomics.
// ---------------------------------------------------------------------------
__global__ __launch_bounds__(256) void k_gemm1(const u16* __restrict__ Wb,
                                               const float* __restrict__ bias,
                                               const u16* __restrict__ xT,
                                               u16* __restrict__ y1T,
                                               float* __restrict__ sum,
                                               float* __restrict__ sumsq) {
  __shared__ u16 As[128 * 32];
  __shared__ u16 Bs[128 * 32];
  __shared__ float s_sum[128], s_ssq[128];
  const int b = blockIdx.z, bm0 = blockIdx.y * 128, bn0 = blockIdx.x * 128;
  const int tid = threadIdx.x, w = tid >> 6, l = tid & 63;
  const int wm = w & 1, wn = w >> 1;
  const int lr = l >> 2, lc = l & 3;
  const int fm = l & 15, fq = l >> 4;
  const int clog = (lc ^ ((lr >> 1) & 3)) * 8;   // staging source k-chunk
  const int swz8 = (fq ^ ((fm >> 1) & 3)) * 8;   // fragment phys k-chunk
  if (tid < 128) { s_sum[tid] = 0.f; s_ssq[tid] = 0.f; }
  f32x4 acc[4][4];
#pragma unroll
  for (int i = 0; i < 4; ++i)
#pragma unroll
    for (int j = 0; j < 4; ++j) acc[i][j] = (f32x4){0.f, 0.f, 0.f, 0.f};

  for (int k0 = 0; k0 < CIN_; k0 += 32) {
    __syncthreads();
#pragma unroll
    for (int j = 0; j < 2; ++j) {
      int seg = w * 2 + j;
      int row = seg * 16 + lr;
      const u16* ga = Wb + (size_t)(bm0 + row) * CIN_ + k0 + clog;
      const u16* gb = xT + ((size_t)b * N_ + bn0 + row) * CIN_ + k0 + clog;
      GLD16(ga, &As[seg * 512]);
      GLD16(gb, &Bs[seg * 512]);
    }
    __syncthreads();
    short8 af[4], bfr[4];
#pragma unroll
    for (int f = 0; f < 4; ++f) {
      af[f]  = *(const short8*)&As[(wm * 64 + f * 16 + fm) * 32 + swz8];
      bfr[f] = *(const short8*)&Bs[(wn * 64 + f * 16 + fm) * 32 + swz8];
    }
#pragma unroll
    for (int i = 0; i < 4; ++i)
#pragma unroll
      for (int j = 0; j < 4; ++j)
        acc[i][j] = __builtin_amdgcn_mfma_f32_16x16x32_bf16(af[i], bfr[j], acc[i][j], 0, 0, 0);
  }
#pragma unroll
  for (int i = 0; i < 4; ++i) {
    int ob = bm0 + wm * 64 + i * 16 + fq * 4;
    float4 b4 = *(const float4*)(bias + ob);
    float sv0 = 0, sv1 = 0, sv2 = 0, sv3 = 0, qv0 = 0, qv1 = 0, qv2 = 0, qv3 = 0;
#pragma unroll
    for (int j = 0; j < 4; ++j) {
      int n = bn0 + wn * 64 + j * 16 + fm;
      ushort4 pk;
      pk.x = f2bf(acc[i][j][0] + b4.x);
      pk.y = f2bf(acc[i][j][1] + b4.y);
      pk.z = f2bf(acc[i][j][2] + b4.z);
      pk.w = f2bf(acc[i][j][3] + b4.w);
      *(ushort4*)(y1T + ((size_t)b * N_ + n) * CMID_ + ob) = pk;
      float v0 = bflo(pk.x), v1 = bflo(pk.y), v2 = bflo(pk.z), v3 = bflo(pk.w);
      sv0 += v0; sv1 += v1; sv2 += v2; sv3 += v3;
      qv0 = fmaf(v0, v0, qv0); qv1 = fmaf(v1, v1, qv1);
      qv2 = fmaf(v2, v2, qv2); qv3 = fmaf(v3, v3, qv3);
    }
#pragma unroll
    for (int m = 1; m <= 8; m <<= 1) {
      sv0 += __shfl_xor(sv0, m); sv1 += __shfl_xor(sv1, m);
      sv2 += __shfl_xor(sv2, m); sv3 += __shfl_xor(sv3, m);
      qv0 += __shfl_xor(qv0, m); qv1 += __shfl_xor(qv1, m);
      qv2 += __shfl_xor(qv2, m); qv3 += __shfl_xor(qv3, m);
    }
    if (fm == 0) {
      int ol = wm * 64 + i * 16 + fq * 4;
      atomicAdd(&s_sum[ol + 0], sv0); atomicAdd(&s_sum[ol + 1], sv1);
      atomicAdd(&s_sum[ol + 2], sv2); atomicAdd(&s_sum[ol + 3], sv3);
      atomicAdd(&s_ssq[ol + 0], qv0); atomicAdd(&s_ssq[ol + 1], qv1);
      atomicAdd(&s_ssq[ol + 2], qv2); atomicAdd(&s_ssq[ol + 3], qv3);
    }
  }
  __syncthreads();
  if (tid < 128) {
    atomicAdd(&sum[bm0 + tid], s_sum[tid]);
    atomicAdd(&sumsq[bm0 + tid], s_ssq[tid]);
  }
}

__global__ __launch_bounds__(256) void k_affine(const float* __restrict__ sum,
                                                const float* __restrict__ sumsq,
                                                const float* __restrict__ g,
                                                const float* __restrict__ beta,
                                                float* __restrict__ scale,
                                                float* __restrict__ shift) {
  int o = threadIdx.x;
  const float inv = 1.0f / (float)(B_ * N_);
  float m = sum[o] * inv;
  float var = sumsq[o] * inv - m * m;
  float sc = g[o] / sqrtf(var + 1e-5f);
  scale[o] = sc;
  shift[o] = beta[o] - m * sc;
}

// ---------------------------------------------------------------------------
// GEMM2 (bf16 MFMA): y2T[b][n][o] = bf16( w2[o][:].relu(bn1(y1T[b][n][:])) + b2[o] )
// Same XOR swizzle; Bs (VALU-staged) writes to the swizzled phys chunk.
// ---------------------------------------------------------------------------
__global__ __launch_bounds__(256) void k_gemm2(const u16* __restrict__ Wb2,
                                               const float* __restrict__ b2,
                                               const u16* __restrict__ y1T,
                                               const float* __restrict__ scale,
                                               const float* __restrict__ shift,
                                               u16* __restrict__ y2T,
                                               float* __restrict__ sum,
                                               float* __restrict__ sumsq) {
  __shared__ u16 As[128 * 32];
  __shared__ u16 Bs[128 * 32];
  __shared__ float s_sum[128], s_ssq[128];
  const int b = blockIdx.z, bm0 = blockIdx.y * 128, bn0 = blockIdx.x * 128;
  const int tid = threadIdx.x, w = tid >> 6, l = tid & 63;
  const int wm = w & 1, wn = w >> 1;
  const int lr = l >> 2, lc = l & 3;
  const int fm = l & 15, fq = l >> 4;
  const int clog = (lc ^ ((lr >> 1) & 3)) * 8;
  const int swz8 = (fq ^ ((fm >> 1) & 3)) * 8;
  if (tid < 128) { s_sum[tid] = 0.f; s_ssq[tid] = 0.f; }
  f32x4 acc[4][4];
#pragma unroll
  for (int i = 0; i < 4; ++i)
#pragma unroll
    for (int j = 0; j < 4; ++j) acc[i][j] = (f32x4){0.f, 0.f, 0.f, 0.f};

  for (int k0 = 0; k0 < CMID_; k0 += 32) {
    __syncthreads();
#pragma unroll
    for (int j = 0; j < 2; ++j) {
      int seg = w * 2 + j;
      int row = seg * 16 + lr;
      const u16* ga = Wb2 + (size_t)(bm0 + row) * CMID_ + k0 + clog;
      GLD16(ga, &As[seg * 512]);
    }
#pragma unroll
    for (int i = 0; i < 2; ++i) {
      int li = tid + i * 256;          // 0..511 16B-chunks
      int n = li >> 2, cp = li & 3;
      int c = k0 + cp * 8;
      uint4 r = *(const uint4*)(y1T + ((size_t)b * N_ + bn0 + n) * CMID_ + c);
      float4 sA = *(const float4*)(scale + c);
      float4 sB = *(const float4*)(scale + c + 4);
      float4 hA = *(const float4*)(shift + c);
      float4 hB = *(const float4*)(shift + c + 4);
      float v0 = fmaxf(fmaf(bflo(r.x), sA.x, hA.x), 0.f);
      float v1 = fmaxf(fmaf(bfhi(r.x), sA.y, hA.y), 0.f);
      float v2 = fmaxf(fmaf(bflo(r.y), sA.z, hA.z), 0.f);
      float v3 = fmaxf(fmaf(bfhi(r.y), sA.w, hA.w), 0.f);
      float v4 = fmaxf(fmaf(bflo(r.z), sB.x, hB.x), 0.f);
      float v5 = fmaxf(fmaf(bfhi(r.z), sB.y, hB.y), 0.f);
      float v6 = fmaxf(fmaf(bflo(r.w), sB.z, hB.z), 0.f);
      float v7 = fmaxf(fmaf(bfhi(r.w), sB.w, hB.w), 0.f);
      uint4 pk;
      pk.x = (u32)f2bf(v0) | ((u32)f2bf(v1) << 16);
      pk.y = (u32)f2bf(v2) | ((u32)f2bf(v3) << 16);
      pk.z = (u32)f2bf(v4) | ((u32)f2bf(v5) << 16);
      pk.w = (u32)f2bf(v6) | ((u32)f2bf(v7) << 16);
      int cph = cp ^ ((n >> 1) & 3);   // swizzled physical chunk
      *(uint4*)&Bs[n * 32 + cph * 8] = pk;
    }
    __syncthreads();
    short8 af[4], bfr[4];
#pragma unroll
    for (int f = 0; f < 4; ++f) {
      af[f]  = *(const short8*)&As[(wm * 64 + f * 16 + fm) * 32 + swz8];
      bfr[f] = *(const short8*)&Bs[(wn * 64 + f * 16 + fm) * 32 + swz8];
    }
#pragma unroll
    for (int i = 0; i < 4; ++i)
#pragma unroll
      for (int j = 0; j < 4; ++j)
        acc[i][j] = __builtin_amdgcn_mfma_f32_16x16x32_bf16(af[i], bfr[j], acc[i][j], 0, 0, 0);
  }
#pragma unroll
  for (int i = 0; i < 4; ++i) {
    int ob = bm0 + wm * 64 + i * 16 + fq * 4;
    float4 b4 = *(const float4*)(b2 + ob);
    float sv0 = 0, sv1 = 0, sv2 = 0, sv3 = 0, qv0 = 0, qv1 = 0, qv2 = 0, qv3 = 0;
#pragma unroll
    for (int j = 0; j < 4; ++j) {
      int n = bn0 + wn * 64 + j * 16 + fm;
      ushort4 pk;
      pk.x = f2bf(acc[i][j][0] + b4.x);
      pk.y = f2bf(acc[i][j][1] + b4.y);
      pk.z = f2bf(acc[i][j][2] + b4.z);
      pk.w = f2bf(acc[i][j][3] + b4.w);
      *(ushort4*)(y2T + ((size_t)b * N_ + n) * COUT_ + ob) = pk;
      float v0 = bflo(pk.x), v1 = bflo(pk.y), v2 = bflo(pk.z), v3 = bflo(pk.w);
      sv0 += v0; sv1 += v1; sv2 += v2; sv3 += v3;
      qv0 = fmaf(v0, v0, qv0); qv1 = fmaf(v1, v1, qv1);
      qv2 = fmaf(v2, v2, qv2); qv3 = fmaf(v3, v3, qv3);
    }
#pragma unroll
    for (int m = 1; m <= 8; m <<= 1) {
      sv0 += __shfl_xor(sv0, m); sv1 += __shfl_xor(sv1, m);
      sv2 += __shfl_xor(sv2, m); sv3 += __shfl_xor(sv3, m);
      qv0 += __shfl_xor(qv0, m); qv1 += __shfl_xor(qv1, m);
      qv2 += __shfl_xor(qv2, m); qv3 += __shfl_xor(qv3, m);
    }
    if (fm == 0) {
      int ol = wm * 64 + i * 16 + fq * 4;
      atomicAdd(&s_sum[ol + 0], sv0); atomicAdd(&s_sum[ol + 1], sv1);
      atomicAdd(&s_sum[ol + 2], sv2); atomicAdd(&s_sum[ol + 3], sv3);
      atomicAdd(&s_ssq[ol + 0], qv0); atomicAdd(&s_ssq[ol + 1], qv1);
      atomicAdd(&s_ssq[ol + 2], qv2); atomicAdd(&s_ssq[ol + 3], qv3);
    }
  }
  __syncthreads();
  if (tid < 128) {
    atomicAdd(&sum[bm0 + tid], s_sum[tid]);
    atomicAdd(&sumsq[bm0 + tid], s_ssq[tid]);
  }
}

// ---------------------------------------------------------------------------
// BN2 + ReLU + transpose: y2T bf16 [b][n][o] -> out fp32 [b][o][n]
// ---------------------------------------------------------------------------
__global__ __launch_bounds__(256) void k_bn2t(const u16* __restrict__ y2T,
                                              const float* __restrict__ scale,
                                              const float* __restrict__ shift,
                                              float* __restrict__ out) {
  __shared__ float t[32][33];
  const int b = blockIdx.z, n0 = blockIdx.x * 32, o0 = blockIdx.y * 32;
  const int cc = threadIdx.x & 31, rr = threadIdx.x >> 5;
  const float sc = scale[o0 + cc], sh = shift[o0 + cc];
#pragma unroll
  for (int i = 0; i < 4; ++i) {
    int r = rr + i * 8;  // n-local
    float v = bflo((u32)y2T[((size_t)b * N_ + n0 + r) * COUT_ + o0 + cc]);
    t[r][cc] = fmaxf(fmaf(v, sc, sh), 0.f);
  }
  __syncthreads();
#pragma unroll
  for (int i = 0; i < 4; ++i) {
    int r = rr + i * 8;  // o-local
    out[((size_t)b * COUT_ + o0 + r) * N_ + n0 + cc] = t[cc][r];
  }
}

// ---------------------------------------------------------------------------
extern "C" void kernel_launch(void* const* d_in, const int* in_sizes, int n_in,
                              void* d_out, int out_size, void* d_ws, size_t ws_size,
                              hipStream_t stream) {
  const float* xyz1    = (const float*)d_in[0];
  const float* xyz2    = (const float*)d_in[1];
  const float* points1 = (const float*)d_in[2];
  const float* points2 = (const float*)d_in[3];
  const float* w1      = (const float*)d_in[4];
  const float* b1      = (const float*)d_in[5];
  const float* g1      = (const float*)d_in[6];
  const float* beta1   = (const float*)d_in[7];
  const float* w2      = (const float*)d_in[8];
  const float* b2      = (const float*)d_in[9];
  const float* g2      = (const float*)d_in[10];
  const float* beta2   = (const float*)d_in[11];
  float* out = (float*)d_out;

  char* ws = (char*)d_ws;
  size_t off = 0;
  u16*    xT    = (u16*)(ws + off);    off += (size_t)B_ * N_ * CIN_ * 2;   // 50.3 MB
  u16*    y1T   = (u16*)(ws + off);    off += (size_t)B_ * N_ * CMID_ * 2;  // 33.6 MB
  float*  p2T   = (float*)(ws + off);  off += (size_t)B_ * S_ * D2_ * 4;    // 16.8 MB
  float4* pts4  = (float4*)(ws + off); off += (size_t)B_ * S_ * 16;         // 0.26 MB
  uint4*  keys  = (uint4*)(ws + off);  off += (size_t)B_ * 8 * N_ * 16;     // 8 MB
  int4*   idx4  = (int4*)(ws + off);   off += (size_t)B_ * N_ * 16;         // 1 MB
  float4* w4    = (float4*)(ws + off); off += (size_t)B_ * N_ * 16;         // 1 MB
  u16*    w1b   = (u16*)(ws + off);    off += (size_t)CMID_ * CIN_ * 2;
  u16*    w2b   = (u16*)(ws + off);    off += (size_t)COUT_ * CMID_ * 2;
  float*  stats = (float*)(ws + off);
  u16*    y2T   = xT;  // alias: xT is dead after k_gemm1
  // stats: [0]=sum1 [256]=sumsq1 [512]=sum2 [768]=sumsq2
  //        [1024]=scale1 [1280]=shift1 [1536]=scale2 [1792]=shift2

  hipMemsetAsync(stats, 0, 1024 * sizeof(float), stream);

  k_wcvt       <<<dim3((CMID_ * CIN_ + COUT_ * CMID_) / 256), 256, 0, stream>>>(w1, w2, w1b, w2b);
  k_prep       <<<dim3(S_ / 256, B_), 256, 0, stream>>>(xyz2, pts4);
  k_p2t        <<<dim3(S_ / 32, D2_ / 32, B_), 256, 0, stream>>>(points2, p2T);
  k_nn_scan    <<<dim3(N_ / 256, 8, B_), 256, 0, stream>>>(xyz1, pts4, keys);
  k_refine     <<<dim3(N_ / 256, B_), 256, 0, stream>>>(xyz1, pts4, keys, idx4, w4);
  k_packp1     <<<dim3(N_ / 32, D1_ / 32, B_), 256, 0, stream>>>(points1, xT);
  k_gather_pack<<<dim3(N_ / 16, B_), 256, 0, stream>>>(p2T, idx4, w4, xT);
  k_gemm1      <<<dim3(N_ / 128, CMID_ / 128, B_), 256, 0, stream>>>(w1b, b1, xT, y1T,
                                                                     stats + 0, stats + 256);
  k_affine     <<<1, 256, 0, stream>>>(stats + 0, stats + 256, g1, beta1, stats + 1024, stats + 1280);
  k_gemm2      <<<dim3(N_ / 128, COUT_ / 128, B_), 256, 0, stream>>>(w2b, b2, y1T,
                                                                     stats + 1024, stats + 1280,
                                                                     y2T, stats + 512, stats + 768);
  k_affine     <<<1, 256, 0, stream>>>(stats + 512, stats + 768, g2, beta2, stats + 1536, stats + 1792);
  k_bn2t       <<<dim3(N_ / 32, COUT_ / 32, B_), 256, 0, stream>>>(y2T, stats + 1536, stats + 1792, out);
}

// Round 8
// 295.699 us; speedup vs baseline: 1.0143x; 1.0143x over previous
//
#include <hip/hip_runtime.h>

#define B_    8
#define N_    8192
#define S_    2048
#define D1_   128
#define D2_   256
#define CIN_  384
#define CMID_ 256
#define COUT_ 256

typedef unsigned int  u32;
typedef unsigned short u16;
typedef __attribute__((ext_vector_type(8))) short short8;
typedef __attribute__((ext_vector_type(4))) float f32x4;

static __device__ __forceinline__ u32 uminu(u32 a, u32 b) { return a < b ? a : b; }
static __device__ __forceinline__ u32 umaxu(u32 a, u32 b) { return a > b ? a : b; }
// guaranteed single v_med3_u32 (the min/max composition was not pattern-matching)
static __device__ __forceinline__ u32 umed3(u32 a, u32 b, u32 c) {
  u32 d;
  asm("v_med3_u32 %0, %1, %2, %3" : "=v"(d) : "v"(a), "v"(b), "v"(c));
  return d;
}
static __device__ __forceinline__ u16 f2bf(float f) {
  union { float f; u32 u; } v; v.f = f;
  u32 r = v.u + 0x7FFFu + ((v.u >> 16) & 1u);  // RNE
  return (u16)(r >> 16);
}
static __device__ __forceinline__ float bflo(u32 u) { return __uint_as_float(u << 16); }
static __device__ __forceinline__ float bfhi(u32 u) { return __uint_as_float(u & 0xFFFF0000u); }

#define GLD16(g, l)                                                             \
  __builtin_amdgcn_global_load_lds((const __attribute__((address_space(1))) void*)(g), \
                                   (__attribute__((address_space(3))) void*)(l), 16, 0, 0)

// ---------------------------------------------------------------------------
// Prep: pts4[b][s] = (-2x, -2y, -2z, |q|^2_f32)
// ---------------------------------------------------------------------------
__global__ __launch_bounds__(256) void k_prep(const float* __restrict__ xyz2,
                                              float4* __restrict__ pts4) {
  const int b = blockIdx.y, s = blockIdx.x * 256 + threadIdx.x;
  const float* xb = xyz2 + (size_t)b * 3 * S_;
  float x = xb[s], y = xb[S_ + s], z = xb[2 * S_ + s];
  pts4[b * S_ + s] = make_float4(-2.f * x, -2.f * y, -2.f * z, x * x + y * y + z * z);
}

// ---------------------------------------------------------------------------
// NN screen: fp32 distance, key = (bits & 0xFFFFFF00) | s_local (15 mantissa
// bits). Top-4 per (n, chunk): min/max + 2x v_med3_u32 + min = 5 VALU.
// 8 chunks of 256 -> 8192 waves. Points via wave-uniform s_loads.
// ---------------------------------------------------------------------------
__global__ __launch_bounds__(256) void k_nn_scan(const float* __restrict__ xyz1,
                                                 const float4* __restrict__ pts4,
                                                 uint4* __restrict__ keys) {
  const int b = blockIdx.z, chunk = blockIdx.y;
  const int n = blockIdx.x * 256 + threadIdx.x;
  const float* pb = xyz1 + (size_t)b * 3 * N_;
  const float px = pb[n], py = pb[N_ + n], pz = pb[2 * N_ + n];
  const float pn = px * px + py * py + pz * pz;
  const float4* __restrict__ P = pts4 + b * S_ + chunk * 256;
  u32 m0 = ~0u, m1 = ~0u, m2 = ~0u, m3 = ~0u;
#pragma unroll 8
  for (int s = 0; s < 256; ++s) {
    float4 q = P[s];  // uniform address -> s_load_dwordx4
    float d = fmaf(px, q.x, fmaf(py, q.y, fmaf(pz, q.z, pn + q.w)));
    d = fmaxf(d, 0.f);
    u32 k = (__float_as_uint(d) & 0xFFFFFF00u) | (u32)s;
    m3 = uminu(m3, umaxu(m2, k));   // uses old m2
    m2 = umed3(m1, m2, k);          // old m1, m2
    m1 = umed3(m0, m1, k);          // old m0, m1
    m0 = uminu(m0, k);
  }
  uint4 v; v.x = m0; v.y = m1; v.z = m2; v.w = m3;
  keys[((size_t)(b * 8 + chunk)) * N_ + n] = v;
}

// ---------------------------------------------------------------------------
// Refine: exact fp64 distances over the 32 candidates, lexicographic (d, idx)
// top-3 -> weights.
// ---------------------------------------------------------------------------
__global__ __launch_bounds__(256) void k_refine(const float* __restrict__ xyz1,
                                                const float4* __restrict__ pts4,
                                                const uint4* __restrict__ keys,
                                                int4* __restrict__ idx4,
                                                float4* __restrict__ w4) {
  const int b = blockIdx.y, n = blockIdx.x * 256 + threadIdx.x;
  const float* pb = xyz1 + (size_t)b * 3 * N_;
  const double px = (double)pb[n], py = (double)pb[N_ + n], pz = (double)pb[2 * N_ + n];
  const double pn = px * px + py * py + pz * pz;
  double bd0 = 1e300, bd1 = 1e300, bd2 = 1e300;
  int bi0 = 1 << 30, bi1 = 1 << 30, bi2 = 1 << 30;
#pragma unroll
  for (int c = 0; c < 8; ++c) {
    uint4 kk = keys[((size_t)(b * 8 + c)) * N_ + n];
    u32 arr[4] = {kk.x, kk.y, kk.z, kk.w};
#pragma unroll
    for (int j = 0; j < 4; ++j) {
      int s = c * 256 + (int)(arr[j] & 255u);
      float4 q = pts4[b * S_ + s];
      double x = (double)(q.x * -0.5f), y = (double)(q.y * -0.5f), z = (double)(q.z * -0.5f);
      double dot = px * x + py * y + pz * z;
      double d = -2.0 * dot + (pn + (x * x + y * y + z * z));
      if (d < bd2 || (d == bd2 && s < bi2)) {
        if (d < bd1 || (d == bd1 && s < bi1)) {
          bd2 = bd1; bi2 = bi1;
          if (d < bd0 || (d == bd0 && s < bi0)) { bd1 = bd0; bi1 = bi0; bd0 = d; bi0 = s; }
          else                                  { bd1 = d;  bi1 = s; }
        } else { bd2 = d; bi2 = s; }
      }
    }
  }
  float f0 = (float)bd0, f1 = (float)bd1, f2 = (float)bd2;
  float r0 = 1.f / (f0 + 1e-8f), r1 = 1.f / (f1 + 1e-8f), r2 = 1.f / (f2 + 1e-8f);
  float rs = r0 + r1 + r2;
  w4[(size_t)b * N_ + n]   = make_float4(r0 / rs, r1 / rs, r2 / rs, 0.f);
  idx4[(size_t)b * N_ + n] = make_int4(bi0, bi1, bi2, 0);
}

// ---------------------------------------------------------------------------
// Transpose points2 [b][256][2048] -> p2T [b][2048][256]
// ---------------------------------------------------------------------------
__global__ __launch_bounds__(256) void k_p2t(const float* __restrict__ p2,
                                             float* __restrict__ p2T) {
  __shared__ float t[32][33];
  const int b = blockIdx.z, s0 = blockIdx.x * 32, d0 = blockIdx.y * 32;
  const int cc = threadIdx.x & 31, rr = threadIdx.x >> 5;
#pragma unroll
  for (int i = 0; i < 4; ++i) {
    int r = rr + i * 8;
    t[r][cc] = p2[((size_t)b * D2_ + d0 + r) * S_ + s0 + cc];
  }
  __syncthreads();
#pragma unroll
  for (int i = 0; i < 4; ++i) {
    int r = rr + i * 8;
    p2T[((size_t)b * S_ + s0 + r) * D2_ + d0 + cc] = t[cc][r];
  }
}

// ---------------------------------------------------------------------------
// points1 [b][128][N] -> xT[b][n][0..127] bf16
// ---------------------------------------------------------------------------
__global__ __launch_bounds__(256) void k_packp1(const float* __restrict__ p1,
                                                u16* __restrict__ xT) {
  __shared__ float t[32][33];
  const int b = blockIdx.z, n0 = blockIdx.x * 32, c0 = blockIdx.y * 32;
  const int cc = threadIdx.x & 31, rr = threadIdx.x >> 5;
#pragma unroll
  for (int i = 0; i < 4; ++i) {
    int r = rr + i * 8;
    t[r][cc] = p1[((size_t)b * D1_ + c0 + r) * N_ + n0 + cc];
  }
  __syncthreads();
#pragma unroll
  for (int i = 0; i < 4; ++i) {
    int r = rr + i * 8;
    xT[((size_t)b * N_ + n0 + r) * CIN_ + c0 + cc] = f2bf(t[cc][r]);
  }
}

// ---------------------------------------------------------------------------
// Gather+interp into xT[b][n][128..383] bf16. One WAVE per point n.
// ---------------------------------------------------------------------------
__global__ __launch_bounds__(256) void k_gather_pack(const float* __restrict__ p2T,
                                                     const int4* __restrict__ idx4,
                                                     const float4* __restrict__ w4,
                                                     u16* __restrict__ xT) {
  const int b = blockIdx.y;
  const int wv = threadIdx.x >> 6, lane = threadIdx.x & 63;
  const int nbase = blockIdx.x * 16 + wv * 4;
  int4   id[4];
  float4 w[4];
#pragma unroll
  for (int i = 0; i < 4; ++i) {
    id[i] = idx4[(size_t)b * N_ + nbase + i];
    w[i]  = w4[(size_t)b * N_ + nbase + i];
  }
#pragma unroll
  for (int i = 0; i < 4; ++i) {
    const int n = nbase + i;
    const float4* r0 = (const float4*)(p2T + ((size_t)b * S_ + id[i].x) * D2_) + lane;
    const float4* r1 = (const float4*)(p2T + ((size_t)b * S_ + id[i].y) * D2_) + lane;
    const float4* r2 = (const float4*)(p2T + ((size_t)b * S_ + id[i].z) * D2_) + lane;
    float4 a = *r0, bb = *r1, cq = *r2;
    ushort4 pk;
    pk.x = f2bf(a.x * w[i].x + bb.x * w[i].y + cq.x * w[i].z);
    pk.y = f2bf(a.y * w[i].x + bb.y * w[i].y + cq.y * w[i].z);
    pk.z = f2bf(a.z * w[i].x + bb.z * w[i].y + cq.z * w[i].z);
    pk.w = f2bf(a.w * w[i].x + bb.w * w[i].y + cq.w * w[i].z);
    *(ushort4*)(xT + ((size_t)b * N_ + n) * CIN_ + D1_ + lane * 4) = pk;
  }
}

// ---------------------------------------------------------------------------
// Convert w1, w2 to bf16
// ---------------------------------------------------------------------------
__global__ __launch_bounds__(256) void k_wcvt(const float* __restrict__ w1,
                                              const float* __restrict__ w2,
                                              u16* __restrict__ w1b,
                                              u16* __restrict__ w2b) {
  int i = blockIdx.x * 256 + threadIdx.x;
  if (i < CMID_ * CIN_) w1b[i] = f2bf(w1[i]);
  int j = i - CMID_ * CIN_;
  if (j >= 0 && j < COUT_ * CMID_) w2b[j] = f2bf(w2[j]);
}

// ---------------------------------------------------------------------------
// GEMM1 (bf16 MFMA), DOUBLE-BUFFERED: barrier; issue tile k+1 GLD16s; then
// ds_read+MFMA tile k. The vmcnt(0) drain at the next barrier lands after a
// full compute phase. XOR k-chunk swizzle kept. Fused BN1 stats (shfl_xor
// butterfly + distinct-address LDS atomics).
// ---------------------------------------------------------------------------
__global__ __launch_bounds__(256) void k_gemm1(const u16* __restrict__ Wb,
                                               const float* __restrict__ bias,
                                               const u16* __restrict__ xT,
                                               u16* __restrict__ y1T,
                                               float* __restrict__ sum,
                                               float* __restrict__ sumsq) {
  __shared__ u16 As[2][4096];
  __shared__ u16 Bs[2][4096];
  __shared__ float s_sum[128], s_ssq[128];
  const int b = blockIdx.z, bm0 = blockIdx.y * 128, bn0 = blockIdx.x * 128;
  const int tid = threadIdx.x, w = tid >> 6, l = tid & 63;
  const int wm = w & 1, wn = w >> 1;
  const int lr = l >> 2, lc = l & 3;
  const int fm = l & 15, fq = l >> 4;
  const int clog = (lc ^ ((lr >> 1) & 3)) * 8;   // staging source k-chunk
  const int swz8 = (fq ^ ((fm >> 1) & 3)) * 8;   // fragment phys k-chunk
  if (tid < 128) { s_sum[tid] = 0.f; s_ssq[tid] = 0.f; }
  f32x4 acc[4][4];
#pragma unroll
  for (int i = 0; i < 4; ++i)
#pragma unroll
    for (int j = 0; j < 4; ++j) acc[i][j] = (f32x4){0.f, 0.f, 0.f, 0.f};

  const int NK = CIN_ / 32;
  // prologue: stage tile 0 into buffer 0
#pragma unroll
  for (int j = 0; j < 2; ++j) {
    int seg = w * 2 + j, row = seg * 16 + lr;
    GLD16(Wb + (size_t)(bm0 + row) * CIN_ + clog, &As[0][seg * 512]);
    GLD16(xT + ((size_t)b * N_ + bn0 + row) * CIN_ + clog, &Bs[0][seg * 512]);
  }
  for (int kk = 0; kk < NK; ++kk) {
    __syncthreads();                 // drains tile-kk loads (issued last iter)
    const int cur = kk & 1;
    if (kk + 1 < NK) {
      const int k0 = (kk + 1) * 32, nxt = cur ^ 1;
#pragma unroll
      for (int j = 0; j < 2; ++j) {
        int seg = w * 2 + j, row = seg * 16 + lr;
        GLD16(Wb + (size_t)(bm0 + row) * CIN_ + k0 + clog, &As[nxt][seg * 512]);
        GLD16(xT + ((size_t)b * N_ + bn0 + row) * CIN_ + k0 + clog, &Bs[nxt][seg * 512]);
      }
    }
    short8 af[4], bfr[4];
#pragma unroll
    for (int f = 0; f < 4; ++f) {
      af[f]  = *(const short8*)&As[cur][(wm * 64 + f * 16 + fm) * 32 + swz8];
      bfr[f] = *(const short8*)&Bs[cur][(wn * 64 + f * 16 + fm) * 32 + swz8];
    }
#pragma unroll
    for (int i = 0; i < 4; ++i)
#pragma unroll
      for (int j = 0; j < 4; ++j)
        acc[i][j] = __builtin_amdgcn_mfma_f32_16x16x32_bf16(af[i], bfr[j], acc[i][j], 0, 0, 0);
  }
#pragma unroll
  for (int i = 0; i < 4; ++i) {
    int ob = bm0 + wm * 64 + i * 16 + fq * 4;
    float4 b4 = *(const float4*)(bias + ob);
    float sv0 = 0, sv1 = 0, sv2 = 0, sv3 = 0, qv0 = 0, qv1 = 0, qv2 = 0, qv3 = 0;
#pragma unroll
    for (int j = 0; j < 4; ++j) {
      int n = bn0 + wn * 64 + j * 16 + fm;
      ushort4 pk;
      pk.x = f2bf(acc[i][j][0] + b4.x);
      pk.y = f2bf(acc[i][j][1] + b4.y);
      pk.z = f2bf(acc[i][j][2] + b4.z);
      pk.w = f2bf(acc[i][j][3] + b4.w);
      *(ushort4*)(y1T + ((size_t)b * N_ + n) * CMID_ + ob) = pk;
      float v0 = bflo(pk.x), v1 = bflo(pk.y), v2 = bflo(pk.z), v3 = bflo(pk.w);
      sv0 += v0; sv1 += v1; sv2 += v2; sv3 += v3;
      qv0 = fmaf(v0, v0, qv0); qv1 = fmaf(v1, v1, qv1);
      qv2 = fmaf(v2, v2, qv2); qv3 = fmaf(v3, v3, qv3);
    }
#pragma unroll
    for (int m = 1; m <= 8; m <<= 1) {
      sv0 += __shfl_xor(sv0, m); sv1 += __shfl_xor(sv1, m);
      sv2 += __shfl_xor(sv2, m); sv3 += __shfl_xor(sv3, m);
      qv0 += __shfl_xor(qv0, m); qv1 += __shfl_xor(qv1, m);
      qv2 += __shfl_xor(qv2, m); qv3 += __shfl_xor(qv3, m);
    }
    if (fm == 0) {
      int ol = wm * 64 + i * 16 + fq * 4;
      atomicAdd(&s_sum[ol + 0], sv0); atomicAdd(&s_sum[ol + 1], sv1);
      atomicAdd(&s_sum[ol + 2], sv2); atomicAdd(&s_sum[ol + 3], sv3);
      atomicAdd(&s_ssq[ol + 0], qv0); atomicAdd(&s_ssq[ol + 1], qv1);
      atomicAdd(&s_ssq[ol + 2], qv2); atomicAdd(&s_ssq[ol + 3], qv3);
    }
  }
  __syncthreads();
  if (tid < 128) {
    atomicAdd(&sum[bm0 + tid], s_sum[tid]);
    atomicAdd(&sumsq[bm0 + tid], s_ssq[tid]);
  }
}

__global__ __launch_bounds__(256) void k_affine(const float* __restrict__ sum,
                                                const float* __restrict__ sumsq,
                                                const float* __restrict__ g,
                                                const float* __restrict__ beta,
                                                float* __restrict__ scale,
                                                float* __restrict__ shift) {
  int o = threadIdx.x;
  const float inv = 1.0f / (float)(B_ * N_);
  float m = sum[o] * inv;
  float var = sumsq[o] * inv - m * m;
  float sc = g[o] / sqrtf(var + 1e-5f);
  scale[o] = sc;
  shift[o] = beta[o] - m * sc;
}

// ---------------------------------------------------------------------------
// GEMM2 (bf16 MFMA), DOUBLE-BUFFERED. B-tile: global loads issued right after
// the barrier, BN1+ReLU+ds_write placed AFTER the MFMAs so load latency hides
// under compute. Epilogue: bf16 [n][o] store + fused BN2 stats.
// ---------------------------------------------------------------------------
__global__ __launch_bounds__(256) void k_gemm2(const u16* __restrict__ Wb2,
                                               const float* __restrict__ b2,
                                               const u16* __restrict__ y1T,
                                               const float* __restrict__ scale,
                                               const float* __restrict__ shift,
                                               u16* __restrict__ y2T,
                                               float* __restrict__ sum,
                                               float* __restrict__ sumsq) {
  __shared__ u16 As[2][4096];
  __shared__ u16 Bs[2][4096];
  __shared__ float s_sum[128], s_ssq[128];
  const int b = blockIdx.z, bm0 = blockIdx.y * 128, bn0 = blockIdx.x * 128;
  const int tid = threadIdx.x, w = tid >> 6, l = tid & 63;
  const int wm = w & 1, wn = w >> 1;
  const int lr = l >> 2, lc = l & 3;
  const int fm = l & 15, fq = l >> 4;
  const int clog = (lc ^ ((lr >> 1) & 3)) * 8;
  const int swz8 = (fq ^ ((fm >> 1) & 3)) * 8;
  // B-staging indices (per thread, two 16B chunks per tile)
  const int bn_0 = tid >> 2, bcp0 = tid & 3;
  const int bn_1 = (tid + 256) >> 2, bcp1 = (tid + 256) & 3;
  const int bph0 = (bcp0 ^ ((bn_0 >> 1) & 3)) * 8;
  const int bph1 = (bcp1 ^ ((bn_1 >> 1) & 3)) * 8;
  if (tid < 128) { s_sum[tid] = 0.f; s_ssq[tid] = 0.f; }
  f32x4 acc[4][4];
#pragma unroll
  for (int i = 0; i < 4; ++i)
#pragma unroll
    for (int j = 0; j < 4; ++j) acc[i][j] = (f32x4){0.f, 0.f, 0.f, 0.f};

  const int NK = CMID_ / 32;

  // helper lambdas (inlined)
  auto bn_pack = [&](uint4 r, int c) -> uint4 {
    float4 sA = *(const float4*)(scale + c);
    float4 sB = *(const float4*)(scale + c + 4);
    float4 hA = *(const float4*)(shift + c);
    float4 hB = *(const float4*)(shift + c + 4);
    float v0 = fmaxf(fmaf(bflo(r.x), sA.x, hA.x), 0.f);
    float v1 = fmaxf(fmaf(bfhi(r.x), sA.y, hA.y), 0.f);
    float v2 = fmaxf(fmaf(bflo(r.y), sA.z, hA.z), 0.f);
    float v3 = fmaxf(fmaf(bfhi(r.y), sA.w, hA.w), 0.f);
    float v4 = fmaxf(fmaf(bflo(r.z), sB.x, hB.x), 0.f);
    float v5 = fmaxf(fmaf(bfhi(r.z), sB.y, hB.y), 0.f);
    float v6 = fmaxf(fmaf(bflo(r.w), sB.z, hB.z), 0.f);
    float v7 = fmaxf(fmaf(bfhi(r.w), sB.w, hB.w), 0.f);
    uint4 pk;
    pk.x = (u32)f2bf(v0) | ((u32)f2bf(v1) << 16);
    pk.y = (u32)f2bf(v2) | ((u32)f2bf(v3) << 16);
    pk.z = (u32)f2bf(v4) | ((u32)f2bf(v5) << 16);
    pk.w = (u32)f2bf(v6) | ((u32)f2bf(v7) << 16);
    return pk;
  };

  // prologue: tile 0 into buffer 0
  {
#pragma unroll
    for (int j = 0; j < 2; ++j) {
      int seg = w * 2 + j, row = seg * 16 + lr;
      GLD16(Wb2 + (size_t)(bm0 + row) * CMID_ + clog, &As[0][seg * 512]);
    }
    uint4 r0 = *(const uint4*)(y1T + ((size_t)b * N_ + bn0 + bn_0) * CMID_ + bcp0 * 8);
    uint4 r1 = *(const uint4*)(y1T + ((size_t)b * N_ + bn0 + bn_1) * CMID_ + bcp1 * 8);
    *(uint4*)&Bs[0][bn_0 * 32 + bph0] = bn_pack(r0, bcp0 * 8);
    *(uint4*)&Bs[0][bn_1 * 32 + bph1] = bn_pack(r1, bcp1 * 8);
  }
  for (int kk = 0; kk < NK; ++kk) {
    __syncthreads();
    const int cur = kk & 1;
    uint4 r0, r1;
    const bool have = (kk + 1 < NK);
    const int k0n = (kk + 1) * 32, nxt = cur ^ 1;
    if (have) {
      // issue next-tile loads first (latency overlaps the MFMAs below)
      r0 = *(const uint4*)(y1T + ((size_t)b * N_ + bn0 + bn_0) * CMID_ + k0n + bcp0 * 8);
      r1 = *(const uint4*)(y1T + ((size_t)b * N_ + bn0 + bn_1) * CMID_ + k0n + bcp1 * 8);
#pragma unroll
      for (int j = 0; j < 2; ++j) {
        int seg = w * 2 + j, row = seg * 16 + lr;
        GLD16(Wb2 + (size_t)(bm0 + row) * CMID_ + k0n + clog, &As[nxt][seg * 512]);
      }
    }
    short8 af[4], bfr[4];
#pragma unroll
    for (int f = 0; f < 4; ++f) {
      af[f]  = *(const short8*)&As[cur][(wm * 64 + f * 16 + fm) * 32 + swz8];
      bfr[f] = *(const short8*)&Bs[cur][(wn * 64 + f * 16 + fm) * 32 + swz8];
    }
#pragma unroll
    for (int i = 0; i < 4; ++i)
#pragma unroll
      for (int j = 0; j < 4; ++j)
        acc[i][j] = __builtin_amdgcn_mfma_f32_16x16x32_bf16(af[i], bfr[j], acc[i][j], 0, 0, 0);
    if (have) {
      *(uint4*)&Bs[nxt][bn_0 * 32 + bph0] = bn_pack(r0, k0n + bcp0 * 8);
      *(uint4*)&Bs[nxt][bn_1 * 32 + bph1] = bn_pack(r1, k0n + bcp1 * 8);
    }
  }
#pragma unroll
  for (int i = 0; i < 4; ++i) {
    int ob = bm0 + wm * 64 + i * 16 + fq * 4;
    float4 b4 = *(const float4*)(b2 + ob);
    float sv0 = 0, sv1 = 0, sv2 = 0, sv3 = 0, qv0 = 0, qv1 = 0, qv2 = 0, qv3 = 0;
#pragma unroll
    for (int j = 0; j < 4; ++j) {
      int n = bn0 + wn * 64 + j * 16 + fm;
      ushort4 pk;
      pk.x = f2bf(acc[i][j][0] + b4.x);
      pk.y = f2bf(acc[i][j][1] + b4.y);
      pk.z = f2bf(acc[i][j][2] + b4.z);
      pk.w = f2bf(acc[i][j][3] + b4.w);
      *(ushort4*)(y2T + ((size_t)b * N_ + n) * COUT_ + ob) = pk;
      float v0 = bflo(pk.x), v1 = bflo(pk.y), v2 = bflo(pk.z), v3 = bflo(pk.w);
      sv0 += v0; sv1 += v1; sv2 += v2; sv3 += v3;
      qv0 = fmaf(v0, v0, qv0); qv1 = fmaf(v1, v1, qv1);
      qv2 = fmaf(v2, v2, qv2); qv3 = fmaf(v3, v3, qv3);
    }
#pragma unroll
    for (int m = 1; m <= 8; m <<= 1) {
      sv0 += __shfl_xor(sv0, m); sv1 += __shfl_xor(sv1, m);
      sv2 += __shfl_xor(sv2, m); sv3 += __shfl_xor(sv3, m);
      qv0 += __shfl_xor(qv0, m); qv1 += __shfl_xor(qv1, m);
      qv2 += __shfl_xor(qv2, m); qv3 += __shfl_xor(qv3, m);
    }
    if (fm == 0) {
      int ol = wm * 64 + i * 16 + fq * 4;
      atomicAdd(&s_sum[ol + 0], sv0); atomicAdd(&s_sum[ol + 1], sv1);
      atomicAdd(&s_sum[ol + 2], sv2); atomicAdd(&s_sum[ol + 3], sv3);
      atomicAdd(&s_ssq[ol + 0], qv0); atomicAdd(&s_ssq[ol + 1], qv1);
      atomicAdd(&s_ssq[ol + 2], qv2); atomicAdd(&s_ssq[ol + 3], qv3);
    }
  }
  __syncthreads();
  if (tid < 128) {
    atomicAdd(&sum[bm0 + tid], s_sum[tid]);
    atomicAdd(&sumsq[bm0 + tid], s_ssq[tid]);
  }
}

// ---------------------------------------------------------------------------
// BN2 + ReLU + transpose: y2T bf16 [b][n][o] -> out fp32 [b][o][n]
// ---------------------------------------------------------------------------
__global__ __launch_bounds__(256) void k_bn2t(const u16* __restrict__ y2T,
                                              const float* __restrict__ scale,
                                              const float* __restrict__ shift,
                                              float* __restrict__ out) {
  __shared__ float t[32][33];
  const int b = blockIdx.z, n0 = blockIdx.x * 32, o0 = blockIdx.y * 32;
  const int cc = threadIdx.x & 31, rr = threadIdx.x >> 5;
  const float sc = scale[o0 + cc], sh = shift[o0 + cc];
#pragma unroll
  for (int i = 0; i < 4; ++i) {
    int r = rr + i * 8;
    float v = bflo((u32)y2T[((size_t)b * N_ + n0 + r) * COUT_ + o0 + cc]);
    t[r][cc] = fmaxf(fmaf(v, sc, sh), 0.f);
  }
  __syncthreads();
#pragma unroll
  for (int i = 0; i < 4; ++i) {
    int r = rr + i * 8;
    out[((size_t)b * COUT_ + o0 + r) * N_ + n0 + cc] = t[cc][r];
  }
}

// ---------------------------------------------------------------------------
extern "C" void kernel_launch(void* const* d_in, const int* in_sizes, int n_in,
                              void* d_out, int out_size, void* d_ws, size_t ws_size,
                              hipStream_t stream) {
  const float* xyz1    = (const float*)d_in[0];
  const float* xyz2    = (const float*)d_in[1];
  const float* points1 = (const float*)d_in[2];
  const float* points2 = (const float*)d_in[3];
  const float* w1      = (const float*)d_in[4];
  const float* b1      = (const float*)d_in[5];
  const float* g1      = (const float*)d_in[6];
  const float* beta1   = (const float*)d_in[7];
  const float* w2      = (const float*)d_in[8];
  const float* b2      = (const float*)d_in[9];
  const float* g2      = (const float*)d_in[10];
  const float* beta2   = (const float*)d_in[11];
  float* out = (float*)d_out;

  char* ws = (char*)d_ws;
  size_t off = 0;
  u16*    xT    = (u16*)(ws + off);    off += (size_t)B_ * N_ * CIN_ * 2;   // 50.3 MB
  u16*    y1T   = (u16*)(ws + off);    off += (size_t)B_ * N_ * CMID_ * 2;  // 33.6 MB
  float*  p2T   = (float*)(ws + off);  off += (size_t)B_ * S_ * D2_ * 4;    // 16.8 MB
  float4* pts4  = (float4*)(ws + off); off += (size_t)B_ * S_ * 16;         // 0.26 MB
  uint4*  keys  = (uint4*)(ws + off);  off += (size_t)B_ * 8 * N_ * 16;     // 8 MB
  int4*   idx4  = (int4*)(ws + off);   off += (size_t)B_ * N_ * 16;         // 1 MB
  float4* w4    = (float4*)(ws + off); off += (size_t)B_ * N_ * 16;         // 1 MB
  u16*    w1b   = (u16*)(ws + off);    off += (size_t)CMID_ * CIN_ * 2;
  u16*    w2b   = (u16*)(ws + off);    off += (size_t)COUT_ * CMID_ * 2;
  float*  stats = (float*)(ws + off);
  u16*    y2T   = xT;  // alias: xT is dead after k_gemm1
  // stats: [0]=sum1 [256]=sumsq1 [512]=sum2 [768]=sumsq2
  //        [1024]=scale1 [1280]=shift1 [1536]=scale2 [1792]=shift2

  hipMemsetAsync(stats, 0, 1024 * sizeof(float), stream);

  k_wcvt       <<<dim3((CMID_ * CIN_ + COUT_ * CMID_) / 256), 256, 0, stream>>>(w1, w2, w1b, w2b);
  k_prep       <<<dim3(S_ / 256, B_), 256, 0, stream>>>(xyz2, pts4);
  k_p2t        <<<dim3(S_ / 32, D2_ / 32, B_), 256, 0, stream>>>(points2, p2T);
  k_nn_scan    <<<dim3(N_ / 256, 8, B_), 256, 0, stream>>>(xyz1, pts4, keys);
  k_refine     <<<dim3(N_ / 256, B_), 256, 0, stream>>>(xyz1, pts4, keys, idx4, w4);
  k_packp1     <<<dim3(N_ / 32, D1_ / 32, B_), 256, 0, stream>>>(points1, xT);
  k_gather_pack<<<dim3(N_ / 16, B_), 256, 0, stream>>>(p2T, idx4, w4, xT);
  k_gemm1      <<<dim3(N_ / 128, CMID_ / 128, B_), 256, 0, stream>>>(w1b, b1, xT, y1T,
                                                                     stats + 0, stats + 256);
  k_affine     <<<1, 256, 0, stream>>>(stats + 0, stats + 256, g1, beta1, stats + 1024, stats + 1280);
  k_gemm2      <<<dim3(N_ / 128, COUT_ / 128, B_), 256, 0, stream>>>(w2b, b2, y1T,
                                                                     stats + 1024, stats + 1280,
                                                                     y2T, stats + 512, stats + 768);
  k_affine     <<<1, 256, 0, stream>>>(stats + 512, stats + 768, g2, beta2, stats + 1536, stats + 1792);
  k_bn2t       <<<dim3(N_ / 32, COUT_ / 32, B_), 256, 0, stream>>>(y2T, stats + 1536, stats + 1792, out);
}